// Round 10
// baseline (238.673 us; speedup 1.0000x reference)
//
#include <hip/hip_runtime.h>
#include <hip/hip_bf16.h>
#include <stdint.h>

// HGNN layer: out = dv*(H*(de*(H^T*(dv*x))))*W^T + b
// N=20000, E=4096, D=128, f32 inputs.
// R10: gemm2 -> 128n x 128j tile, grid 157 (1 block/CU, critical path 64
// steps vs 128); 3-deep counted-vmcnt pipeline (required: no TLP at 1/CU).
// k_pre/gemm1/k_mid = R8 verbatim (224us components). Hb padded to 20096.

#define N_ 20000
#define E_ 4096
#define D_ 128
#define XTB_S 20032
#define SPLIT 12

typedef __attribute__((ext_vector_type(8))) short    bf16x8;
typedef __attribute__((ext_vector_type(4))) float    f32x4;
typedef __attribute__((ext_vector_type(8))) unsigned short us8;
typedef __attribute__((ext_vector_type(4))) unsigned short us4;

__device__ __forceinline__ unsigned short f2bf(float f) {
  unsigned u = __float_as_uint(f);
  u += 0x7FFFu + ((u >> 16) & 1u);        // RNE
  return (unsigned short)(u >> 16);
}
__device__ __forceinline__ unsigned cvtpk(float lo, float hi) {
  unsigned r;
  asm("v_cvt_pk_bf16_f32 %0, %1, %2" : "=v"(r) : "v"(lo), "v"(hi));
  return r;
}
__device__ __forceinline__ void gload16(const unsigned short* g, unsigned short* l) {
  __builtin_amdgcn_global_load_lds(
      (const __attribute__((address_space(1))) unsigned int*)g,
      (__attribute__((address_space(3))) unsigned int*)l, 16, 0, 0);
}
#define VMCNT(n) asm volatile("s_waitcnt vmcnt(" #n ")" ::: "memory")
#define BAR()    do { __builtin_amdgcn_s_barrier(); __builtin_amdgcn_sched_barrier(0); } while (0)

// ---------------------------------------------------------------------------
// k_pre: rowsum -> dv; Hb[n][e] = bf16(H) (same layout); xTb[d][n] = bf16(dv*x).
// Pad blocks 2500..2511 zero Hb rows 20000..20095; 2500 zeros xTb pad;
// 2501 converts W.
// ---------------------------------------------------------------------------
__global__ __launch_bounds__(256) void k_pre(const float* __restrict__ H,
                                             const float* __restrict__ x,
                                             const float* __restrict__ W,
                                             float* __restrict__ dv,
                                             unsigned short* __restrict__ Hb,
                                             unsigned short* __restrict__ xTb,
                                             unsigned short* __restrict__ Wb) {
  const int t = threadIdx.x, lane = t & 63, w = t >> 6;
  const int b = blockIdx.x;
  if (b >= 2500) {                          // pad + W maintenance
    const size_t base = (size_t)(20000 + (b - 2500) * 8) * E_;
    for (int i = t; i < 4096; i += 256)
      *(us8*)&Hb[base + (size_t)i * 8] = (us8){0,0,0,0,0,0,0,0};
    if (b == 2500 && t < 128) {
#pragma unroll
      for (int c = 0; c < 4; ++c)
        *(us8*)&xTb[(size_t)t * XTB_S + 20000 + c * 8] = (us8){0,0,0,0,0,0,0,0};
    }
    if (b == 2501) {                        // Wb = bf16(W), [j][d]
      int base2 = t * 64;
#pragma unroll
      for (int i = 0; i < 8; ++i) {
        const float* wp = W + base2 + i * 8;
        f32x4 a = *(const f32x4*)wp, b4 = *(const f32x4*)(wp + 4);
        union { us8 v; unsigned u[4]; } un;
        un.u[0] = cvtpk(a.x, a.y);   un.u[1] = cvtpk(a.z, a.w);
        un.u[2] = cvtpk(b4.x, b4.y); un.u[3] = cvtpk(b4.z, b4.w);
        *(us8*)(Wb + base2 + i * 8) = un.v;
      }
    }
    return;
  }
  __shared__ float red[32];
  __shared__ float xt[8 * 128];
  const int n0 = b * 8;
  { int r = t >> 5, d4 = (t & 31) * 4;
    *(f32x4*)&xt[r * 128 + d4] = *(const f32x4*)(x + (size_t)(n0 + r) * D_ + d4); }
  float rs[8];
#pragma unroll
  for (int r = 0; r < 8; ++r) {
    rs[r] = 0.f;
    const float* rp = H + (size_t)(n0 + r) * E_;
    unsigned short* hp = Hb + (size_t)(n0 + r) * E_;
#pragma unroll
    for (int j = 0; j < 4; ++j) {
      f32x4 v = *(const f32x4*)(rp + j * 1024 + t * 4);
      rs[r] += (v.x + v.y) + (v.z + v.w);
      union { us4 v4; unsigned u32[2]; } un;
      un.u32[0] = cvtpk(v.x, v.y);
      un.u32[1] = cvtpk(v.z, v.w);
      *(us4*)(hp + j * 1024 + t * 4) = un.v4;
    }
  }
#pragma unroll
  for (int r = 0; r < 8; ++r)
#pragma unroll
    for (int off = 32; off; off >>= 1) rs[r] += __shfl_xor(rs[r], off);
  if (lane == 0) {
#pragma unroll
    for (int r = 0; r < 8; ++r) red[w * 8 + r] = rs[r];
  }
  __syncthreads();
  if (t < 8) {
    float s = red[t] + red[8 + t] + red[16 + t] + red[24 + t];
    float d = s > 0.f ? rsqrtf(s) : 0.f;
    dv[n0 + t] = d;
    red[t] = d;
  }
  __syncthreads();
  if (t < 128) {
    int d = t;
    float v[8];
#pragma unroll
    for (int r = 0; r < 8; ++r) v[r] = xt[r * 128 + d] * red[r];
    union { us8 v8; unsigned u32[4]; } un;
#pragma unroll
    for (int j = 0; j < 4; ++j) un.u32[j] = cvtpk(v[2 * j], v[2 * j + 1]);
    *(us8*)(xTb + (size_t)d * XTB_S + n0) = un.v8;
  }
}

// ---------------------------------------------------------------------------
// GEMM1 (R8 verbatim): partialT[s][d][e] = sum_{n chunk s} xdv[n][d]*H[n][e]
// Tile 128d x 64e, BK=64, dbuf. A (xTb) via pre-swizzled gload16; B (Hb)
// transposed in LDS (u32 loads + perm unpack + XOR-swizzled b128 writes).
// Colsum via ones-MFMA -> desumP[s][e]. grid = 64 eb * 12 s = 768 (3/CU).
// ---------------------------------------------------------------------------
__global__ __launch_bounds__(256) void k_gemm1(const unsigned short* __restrict__ Hb,
                                               const unsigned short* __restrict__ xTb,
                                               float* __restrict__ partialT,
                                               float* __restrict__ desumP) {
  __shared__ unsigned short lH[2][64 * 64];   // [e][n] transposed, swizzled
  __shared__ unsigned short lX[2][128 * 64];  // [d][n], swizzled content
  const int t = threadIdx.x, lane = t & 63, w = t >> 6;
  const int eb = blockIdx.x & 63, s = blockIdx.x >> 6;  // s in 0..11
  const int e0 = eb * 64;
  const int g0 = (s * 313) / SPLIT;           // 313 BK=64 steps total (incl pad)
  const int g1 = ((s + 1) * 313) / SPLIT;
  const int lrow = lane >> 3, lslot = lane & 7;
  const int bswz = (lslot ^ lrow) << 3;
  const int wy = w >> 1, wx = w & 1;          // wy: d-half(64), wx: e-half(32)
  const int ep = t & 31, q = t >> 5;
  const int er0 = 2 * ep, er1 = 2 * ep + 1;
  const int sl0 = (q ^ (er0 & 7)) << 3, sl1 = (q ^ (er1 & 7)) << 3;

  f32x4 acc[4][2];
  f32x4 accC[2];
#pragma unroll
  for (int i = 0; i < 4; ++i)
#pragma unroll
    for (int j = 0; j < 2; ++j) acc[i][j] = (f32x4){0.f, 0.f, 0.f, 0.f};
  accC[0] = (f32x4){0.f, 0.f, 0.f, 0.f};
  accC[1] = (f32x4){0.f, 0.f, 0.f, 0.f};
  bf16x8 ones;
#pragma unroll
  for (int i = 0; i < 8; ++i) ones[i] = (short)0x3F80;

  unsigned hr[8];
  auto LOADH = [&](int g) {
    const unsigned short* p = Hb + (size_t)(g * 64 + q * 8) * E_ + e0 + er0;
#pragma unroll
    for (int j = 0; j < 8; ++j) hr[j] = *(const unsigned*)(p + (size_t)j * E_);
  };
  auto WRITEH = [&](int bufi) {
    union { bf16x8 v; unsigned u[4]; } lo, hi;
#pragma unroll
    for (int p = 0; p < 4; ++p) {
      lo.u[p] = (hr[2 * p] & 0xFFFFu) | (hr[2 * p + 1] << 16);
      hi.u[p] = (hr[2 * p] >> 16) | (hr[2 * p + 1] & 0xFFFF0000u);
    }
    *(bf16x8*)&lH[bufi][er0 * 64 + sl0] = lo.v;
    *(bf16x8*)&lH[bufi][er1 * 64 + sl1] = hi.v;
  };
  auto GLOADX = [&](int g, int bufi) {
#pragma unroll
    for (int i = 0; i < 4; ++i) {
      int c = w * 4 + i;
      gload16(xTb + (size_t)(8 * c + lrow) * XTB_S + g * 64 + bswz,
              &lX[bufi][c * 512]);
    }
  };

  LOADH(g0); GLOADX(g0, 0); WRITEH(0);
  __syncthreads();
  int cur = 0;
  for (int it = g0; it < g1; ++it) {
    bool hn = it + 1 < g1;
    if (hn) { LOADH(it + 1); GLOADX(it + 1, cur ^ 1); }
    const int kg = lane >> 4, fr = lane & 15;
    bf16x8 ax[4][2], bh[2][2];
#pragma unroll
    for (int mi = 0; mi < 4; ++mi) {
      int m = wy * 64 + mi * 16 + fr;
#pragma unroll
      for (int kk = 0; kk < 2; ++kk)
        ax[mi][kk] = *(const bf16x8*)&lX[cur][m * 64 + (((kk * 4 + kg) ^ (m & 7)) << 3)];
    }
#pragma unroll
    for (int ni = 0; ni < 2; ++ni) {
      int n = wx * 32 + ni * 16 + fr;
#pragma unroll
      for (int kk = 0; kk < 2; ++kk)
        bh[ni][kk] = *(const bf16x8*)&lH[cur][n * 64 + (((kk * 4 + kg) ^ (n & 7)) << 3)];
    }
#pragma unroll
    for (int kk = 0; kk < 2; ++kk)
#pragma unroll
      for (int mi = 0; mi < 4; ++mi)
#pragma unroll
        for (int ni = 0; ni < 2; ++ni)
          acc[mi][ni] = __builtin_amdgcn_mfma_f32_16x16x32_bf16(ax[mi][kk], bh[ni][kk], acc[mi][ni], 0, 0, 0);
    if (wy == 0) {
#pragma unroll
      for (int kk = 0; kk < 2; ++kk)
#pragma unroll
        for (int ni = 0; ni < 2; ++ni)
          accC[ni] = __builtin_amdgcn_mfma_f32_16x16x32_bf16(ones, bh[ni][kk], accC[ni], 0, 0, 0);
    }
    if (hn) WRITEH(cur ^ 1);
    __syncthreads();
    cur ^= 1;
  }
  const int kg = lane >> 4, fr = lane & 15;
  if (wy == 0 && kg == 0) {                   // colsum partial (rows identical)
#pragma unroll
    for (int ni = 0; ni < 2; ++ni)
      desumP[s * E_ + e0 + wx * 32 + ni * 16 + fr] = accC[ni][0];
  }
#pragma unroll
  for (int mi = 0; mi < 4; ++mi)
#pragma unroll
    for (int ni = 0; ni < 2; ++ni)
#pragma unroll
      for (int r = 0; r < 4; ++r) {
        int d = wy * 64 + mi * 16 + kg * 4 + r;
        int e = e0 + wx * 32 + ni * 16 + fr;
        partialT[((size_t)s * 128 + d) * E_ + e] = acc[mi][ni][r];
      }
}

// ---------------------------------------------------------------------------
// k_mid: x3WT[j][e] = sum_d W[j][d] * (de[e] * sum_s partialT[s][d][e])
// 256 blocks x 16 e.
// ---------------------------------------------------------------------------
__global__ __launch_bounds__(256) void k_mid(const float* __restrict__ partialT,
                                             const float* __restrict__ desumP,
                                             const unsigned short* __restrict__ Wb,
                                             unsigned short* __restrict__ x3WT) {
  __shared__ unsigned short lW[128 * 136];    // [j][d] padded
  __shared__ unsigned short lE[16 * 132];     // [e][d] padded
  __shared__ float lT[128 * 20];              // [j][e] padded
  const int t = threadIdx.x, lane = t & 63, w = t >> 6;
  const int e0 = blockIdx.x * 16;

  {                                           // stage Wb -> lW
    int j = t >> 1, half = (t & 1) * 64;
    const us8* src = (const us8*)(Wb + (size_t)j * 128 + half);
#pragma unroll
    for (int i = 0; i < 8; ++i)
      *(us8*)&lW[j * 136 + half + 8 * i] = src[i];
  }
  {                                           // phase 1: reduce + de-scale
    const int e = e0 + (t & 15);
    const int d0 = (t >> 4) * 8;
    float des = 0.f;
#pragma unroll
    for (int s = 0; s < SPLIT; ++s) des += desumP[s * E_ + e];
    float dei = des > 0.f ? 1.f / des : 0.f;
    float accp[8];
#pragma unroll
    for (int i = 0; i < 8; ++i) accp[i] = 0.f;
#pragma unroll
    for (int s = 0; s < SPLIT; ++s) {
      const float* p = partialT + ((size_t)s * 128 + d0) * E_ + e;
#pragma unroll
      for (int i = 0; i < 8; ++i) accp[i] += p[(size_t)i * E_];
    }
    union { bf16x8 v; unsigned u[4]; } un;
#pragma unroll
    for (int i = 0; i < 4; ++i)
      un.u[i] = cvtpk(accp[2 * i] * dei, accp[2 * i + 1] * dei);
    *(bf16x8*)&lE[(t & 15) * 132 + d0] = un.v;
  }
  __syncthreads();
  // phase 2: D[j][e] = W @ x3^T ; 4 waves x (32j x 16e), K=128
  const int kg = lane >> 4, fr = lane & 15;
  f32x4 acc[2];
  acc[0] = (f32x4){0.f, 0.f, 0.f, 0.f};
  acc[1] = (f32x4){0.f, 0.f, 0.f, 0.f};
#pragma unroll
  for (int kk = 0; kk < 4; ++kk) {
    bf16x8 bfrag = *(const bf16x8*)&lE[fr * 132 + (kk * 4 + kg) * 8];
#pragma unroll
    for (int mi = 0; mi < 2; ++mi) {
      int m = w * 32 + mi * 16 + fr;
      bf16x8 afrag = *(const bf16x8*)&lW[m * 136 + (kk * 4 + kg) * 8];
      acc[mi] = __builtin_amdgcn_mfma_f32_16x16x32_bf16(afrag, bfrag, acc[mi], 0, 0, 0);
    }
  }
  __syncthreads();
#pragma unroll
  for (int mi = 0; mi < 2; ++mi)
#pragma unroll
    for (int r = 0; r < 4; ++r)
      lT[(w * 32 + mi * 16 + kg * 4 + r) * 20 + fr] = acc[mi][r];
  __syncthreads();
  {
    int j = t >> 1, eh = (t & 1) * 8;
    float v[8];
#pragma unroll
    for (int i = 0; i < 8; ++i) v[i] = lT[j * 20 + eh + i];
    union { us8 v8; unsigned u[4]; } un;
#pragma unroll
    for (int i = 0; i < 4; ++i) un.u[i] = cvtpk(v[2 * i], v[2 * i + 1]);
    *(us8*)(x3WT + (size_t)j * E_ + e0 + eh) = un.v8;
  }
}

// ---------------------------------------------------------------------------
// GEMM2: out[n][j] = dv[n] * sum_e Hb[n][e]*x3WT[j][e] + b[j]
// 128n x 128j tile, BK=64, grid 157 (1 block/CU, critical path 64 steps).
// 3-deep gload16 pipeline, counted vmcnt(8), raw barrier (no TLP at 1/CU so
// loads MUST stay in flight across the barrier). LDS 96KB.
// ---------------------------------------------------------------------------
__global__ __launch_bounds__(256) void k_gemm2(const unsigned short* __restrict__ Hb,
                                               const unsigned short* __restrict__ x3WT,
                                               const float* __restrict__ dv,
                                               const float* __restrict__ bias,
                                               float* __restrict__ out) {
  __shared__ unsigned short lA[3][128 * 64];  // [n][e] swizzled content
  __shared__ unsigned short lB[3][128 * 64];  // [j][e] swizzled content
  const int t = threadIdx.x, lane = t & 63, w = t >> 6;
  const int n0b = blockIdx.x * 128;
  const int lrow = lane >> 3, lslot = lane & 7;
  const int bswz = (lslot ^ lrow) << 3;
  const int wy = w >> 1, wx = w & 1;          // wave tile: 64n x 64j

  auto STAGE = [&](int g, int bufi) {
#pragma unroll
    for (int i = 0; i < 4; ++i) {
      int c = w * 4 + i;
      gload16(Hb + (size_t)(n0b + 8 * c + lrow) * E_ + g * 64 + bswz,
              &lA[bufi][c * 512]);
    }
#pragma unroll
    for (int i = 0; i < 4; ++i) {
      int c = w * 4 + i;
      gload16(x3WT + (size_t)(8 * c + lrow) * E_ + g * 64 + bswz,
              &lB[bufi][c * 512]);
    }
  };

  f32x4 acc[4][4];
#pragma unroll
  for (int i = 0; i < 4; ++i)
#pragma unroll
    for (int j = 0; j < 4; ++j) acc[i][j] = (f32x4){0.f, 0.f, 0.f, 0.f};

  STAGE(0, 0);                                // 8 loads/wave
  STAGE(1, 1);                                // 8 loads/wave
  VMCNT(8);                                   // step 0 ready; step 1 flying
  BAR();

  int cur = 0;
  for (int it = 0; it < 64; ++it) {
    const int tn = (it + 2 < 64) ? it + 2 : 63;
    STAGE(tn, cur == 0 ? 2 : cur - 1);        // buf (it+2)%3
    const int kg = lane >> 4, fr = lane & 15;
    bf16x8 af[4][2], bfr[4][2];
#pragma unroll
    for (int mi = 0; mi < 4; ++mi) {
      int m = wy * 64 + mi * 16 + fr;
#pragma unroll
      for (int kk = 0; kk < 2; ++kk)
        af[mi][kk] = *(const bf16x8*)&lA[cur][m * 64 + (((kk * 4 + kg) ^ (m & 7)) << 3)];
    }
#pragma unroll
    for (int ni = 0; ni < 4; ++ni) {
      int d = wx * 64 + ni * 16 + fr;
#pragma unroll
      for (int kk = 0; kk < 2; ++kk)
        bfr[ni][kk] = *(const bf16x8*)&lB[cur][d * 64 + (((kk * 4 + kg) ^ (d & 7)) << 3)];
    }
    __builtin_amdgcn_s_setprio(1);
#pragma unroll
    for (int kk = 0; kk < 2; ++kk)
#pragma unroll
      for (int mi = 0; mi < 4; ++mi)
#pragma unroll
        for (int ni = 0; ni < 4; ++ni)
          acc[mi][ni] = __builtin_amdgcn_mfma_f32_16x16x32_bf16(af[mi][kk], bfr[ni][kk], acc[mi][ni], 0, 0, 0);
    __builtin_amdgcn_s_setprio(0);
    VMCNT(8);                                 // next step complete; t+2 flying
    BAR();
    cur = (cur == 2) ? 0 : cur + 1;
  }
  // epilogue: out = dv*acc + bias, direct f32 stores
  const int kg = lane >> 4, fr = lane & 15;
#pragma unroll
  for (int mi = 0; mi < 4; ++mi) {
    float dvv[4];
#pragma unroll
    for (int r = 0; r < 4; ++r)
      dvv[r] = dv[min(n0b + wy * 64 + mi * 16 + kg * 4 + r, N_ - 1)];
#pragma unroll
    for (int ni = 0; ni < 4; ++ni) {
      int j2 = wx * 64 + ni * 16 + fr;
      float bb = bias[j2];
#pragma unroll
      for (int r = 0; r < 4; ++r) {
        int n = n0b + wy * 64 + mi * 16 + kg * 4 + r;
        if (n < N_) out[(size_t)n * D_ + j2] = acc[mi][ni][r] * dvv[r] + bb;
      }
    }
  }
}

// ---------------------------------------------------------------------------
extern "C" void kernel_launch(void* const* d_in, const int* in_sizes, int n_in,
                              void* d_out, int out_size, void* d_ws, size_t ws_size,
                              hipStream_t stream) {
  const float* x = (const float*)d_in[0];
  const float* H = (const float*)d_in[1];
  const float* W = (const float*)d_in[2];
  const float* b = (const float*)d_in[3];
  float* out = (float*)d_out;
  char* ws = (char*)d_ws;
  float*          desumP   = (float*)(ws);                     // 12*4096*4 = 196,608
  float*          dv       = (float*)(ws + 196608);            // 80,128
  unsigned short* Wb       = (unsigned short*)(ws + 276736);   // 32,768
  unsigned short* xTb      = (unsigned short*)(ws + 309504);   // 5,128,192
  unsigned short* x3WT     = (unsigned short*)(ws + 5437696);  // 1,048,576
  float*          partialT = (float*)(ws + 6486272);           // 25,165,824
  unsigned short* Hb       = (unsigned short*)(ws + 31652096); // 20096*4096*2 = 164,626,432

  k_pre<<<2512, 256, 0, stream>>>(H, x, W, dv, Hb, xTb, Wb);
  k_gemm1<<<768, 256, 0, stream>>>(Hb, xTb, partialT, desumP);
  k_mid<<<256, 256, 0, stream>>>(partialT, desumP, Wb, x3WT);
  k_gemm2<<<157, 256, 0, stream>>>(Hb, x3WT, dv, b, out);
}

// Round 11
// 213.663 us; speedup vs baseline: 1.1171x; 1.1171x over previous
//
#include <hip/hip_runtime.h>
#include <hip/hip_bf16.h>
#include <stdint.h>

// HGNN layer: out = dv*(H*(de*(H^T*(dv*x))))*W^T + b
// N=20000, E=4096, D=128, f32 inputs.
// R11: R8 base (best, 224us). gemm2 -> split-K=2 (grid 626, 32 steps/block,
// f32 partials + k_out reduce): balances the 313-block tail (path 128->96)
// without touching the proven 2-phase structure. gemm1 gets an XCD-cluster
// decode so same-s blocks (sharing a 0.43MB xTb slice) land on <=2 XCDs.

#define N_ 20000
#define E_ 4096
#define D_ 128
#define XTB_S 20032
#define SPLIT 12

typedef __attribute__((ext_vector_type(8))) short    bf16x8;
typedef __attribute__((ext_vector_type(4))) float    f32x4;
typedef __attribute__((ext_vector_type(8))) unsigned short us8;
typedef __attribute__((ext_vector_type(4))) unsigned short us4;

__device__ __forceinline__ unsigned short f2bf(float f) {
  unsigned u = __float_as_uint(f);
  u += 0x7FFFu + ((u >> 16) & 1u);        // RNE
  return (unsigned short)(u >> 16);
}
__device__ __forceinline__ unsigned cvtpk(float lo, float hi) {
  unsigned r;
  asm("v_cvt_pk_bf16_f32 %0, %1, %2" : "=v"(r) : "v"(lo), "v"(hi));
  return r;
}
__device__ __forceinline__ void gload16(const unsigned short* g, unsigned short* l) {
  __builtin_amdgcn_global_load_lds(
      (const __attribute__((address_space(1))) unsigned int*)g,
      (__attribute__((address_space(3))) unsigned int*)l, 16, 0, 0);
}

// ---------------------------------------------------------------------------
// k_pre: rowsum -> dv; Hb[n][e] = bf16(H) (same layout); xTb[d][n] = bf16(dv*x).
// Pad blocks 2500..2503 zero Hb pad rows; 2500 zeros xTb pad; 2501 converts W.
// ---------------------------------------------------------------------------
__global__ __launch_bounds__(256) void k_pre(const float* __restrict__ H,
                                             const float* __restrict__ x,
                                             const float* __restrict__ W,
                                             float* __restrict__ dv,
                                             unsigned short* __restrict__ Hb,
                                             unsigned short* __restrict__ xTb,
                                             unsigned short* __restrict__ Wb) {
  const int t = threadIdx.x, lane = t & 63, w = t >> 6;
  const int b = blockIdx.x;
  if (b >= 2500) {                          // pad + W maintenance
    const size_t base = (size_t)(20000 + (b - 2500) * 8) * E_;
    for (int i = t; i < 4096; i += 256)
      *(us8*)&Hb[base + (size_t)i * 8] = (us8){0,0,0,0,0,0,0,0};
    if (b == 2500 && t < 128) {
#pragma unroll
      for (int c = 0; c < 4; ++c)
        *(us8*)&xTb[(size_t)t * XTB_S + 20000 + c * 8] = (us8){0,0,0,0,0,0,0,0};
    }
    if (b == 2501) {                        // Wb = bf16(W), [j][d]
      int base2 = t * 64;
#pragma unroll
      for (int i = 0; i < 8; ++i) {
        const float* wp = W + base2 + i * 8;
        f32x4 a = *(const f32x4*)wp, b4 = *(const f32x4*)(wp + 4);
        union { us8 v; unsigned u[4]; } un;
        un.u[0] = cvtpk(a.x, a.y);   un.u[1] = cvtpk(a.z, a.w);
        un.u[2] = cvtpk(b4.x, b4.y); un.u[3] = cvtpk(b4.z, b4.w);
        *(us8*)(Wb + base2 + i * 8) = un.v;
      }
    }
    return;
  }
  __shared__ float red[32];
  __shared__ float xt[8 * 128];
  const int n0 = b * 8;
  { int r = t >> 5, d4 = (t & 31) * 4;
    *(f32x4*)&xt[r * 128 + d4] = *(const f32x4*)(x + (size_t)(n0 + r) * D_ + d4); }
  float rs[8];
#pragma unroll
  for (int r = 0; r < 8; ++r) {
    rs[r] = 0.f;
    const float* rp = H + (size_t)(n0 + r) * E_;
    unsigned short* hp = Hb + (size_t)(n0 + r) * E_;
#pragma unroll
    for (int j = 0; j < 4; ++j) {
      f32x4 v = *(const f32x4*)(rp + j * 1024 + t * 4);
      rs[r] += (v.x + v.y) + (v.z + v.w);
      union { us4 v4; unsigned u32[2]; } un;
      un.u32[0] = cvtpk(v.x, v.y);
      un.u32[1] = cvtpk(v.z, v.w);
      *(us4*)(hp + j * 1024 + t * 4) = un.v4;
    }
  }
#pragma unroll
  for (int r = 0; r < 8; ++r)
#pragma unroll
    for (int off = 32; off; off >>= 1) rs[r] += __shfl_xor(rs[r], off);
  if (lane == 0) {
#pragma unroll
    for (int r = 0; r < 8; ++r) red[w * 8 + r] = rs[r];
  }
  __syncthreads();
  if (t < 8) {
    float s = red[t] + red[8 + t] + red[16 + t] + red[24 + t];
    float d = s > 0.f ? rsqrtf(s) : 0.f;
    dv[n0 + t] = d;
    red[t] = d;
  }
  __syncthreads();
  if (t < 128) {
    int d = t;
    float v[8];
#pragma unroll
    for (int r = 0; r < 8; ++r) v[r] = xt[r * 128 + d] * red[r];
    union { us8 v8; unsigned u32[4]; } un;
#pragma unroll
    for (int j = 0; j < 4; ++j) un.u32[j] = cvtpk(v[2 * j], v[2 * j + 1]);
    *(us8*)(xTb + (size_t)d * XTB_S + n0) = un.v8;
  }
}

// ---------------------------------------------------------------------------
// GEMM1 (R8 + XCD cluster): partialT[s][d][e] = sum_{n chunk s} xdv[n][d]*H[n][e]
// Tile 128d x 64e, BK=64, dbuf. A (xTb) via pre-swizzled gload16; B (Hb)
// transposed in LDS. Colsum via ones-MFMA -> desumP[s][e]. grid 768 (3/CU).
// Decode virt=(phys&7)*96+(phys>>3): same-s blocks cluster on <=2 XCDs so
// the shared xTb chunk is fetched from HBM once per XCD, not 8x.
// ---------------------------------------------------------------------------
__global__ __launch_bounds__(256) void k_gemm1(const unsigned short* __restrict__ Hb,
                                               const unsigned short* __restrict__ xTb,
                                               float* __restrict__ partialT,
                                               float* __restrict__ desumP) {
  __shared__ unsigned short lH[2][64 * 64];   // [e][n] transposed, swizzled
  __shared__ unsigned short lX[2][128 * 64];  // [d][n], swizzled content
  const int t = threadIdx.x, lane = t & 63, w = t >> 6;
  const int virt = (blockIdx.x & 7) * 96 + (blockIdx.x >> 3);
  const int eb = virt & 63, s = virt >> 6;    // s in 0..11
  const int e0 = eb * 64;
  const int g0 = (s * 313) / SPLIT;           // 313 BK=64 steps total (incl pad)
  const int g1 = ((s + 1) * 313) / SPLIT;
  const int lrow = lane >> 3, lslot = lane & 7;
  const int bswz = (lslot ^ lrow) << 3;
  const int wy = w >> 1, wx = w & 1;          // wy: d-half(64), wx: e-half(32)
  const int ep = t & 31, q = t >> 5;
  const int er0 = 2 * ep, er1 = 2 * ep + 1;
  const int sl0 = (q ^ (er0 & 7)) << 3, sl1 = (q ^ (er1 & 7)) << 3;

  f32x4 acc[4][2];
  f32x4 accC[2];
#pragma unroll
  for (int i = 0; i < 4; ++i)
#pragma unroll
    for (int j = 0; j < 2; ++j) acc[i][j] = (f32x4){0.f, 0.f, 0.f, 0.f};
  accC[0] = (f32x4){0.f, 0.f, 0.f, 0.f};
  accC[1] = (f32x4){0.f, 0.f, 0.f, 0.f};
  bf16x8 ones;
#pragma unroll
  for (int i = 0; i < 8; ++i) ones[i] = (short)0x3F80;

  unsigned hr[8];
  auto LOADH = [&](int g) {
    const unsigned short* p = Hb + (size_t)(g * 64 + q * 8) * E_ + e0 + er0;
#pragma unroll
    for (int j = 0; j < 8; ++j) hr[j] = *(const unsigned*)(p + (size_t)j * E_);
  };
  auto WRITEH = [&](int bufi) {
    union { bf16x8 v; unsigned u[4]; } lo, hi;
#pragma unroll
    for (int p = 0; p < 4; ++p) {
      lo.u[p] = (hr[2 * p] & 0xFFFFu) | (hr[2 * p + 1] << 16);
      hi.u[p] = (hr[2 * p] >> 16) | (hr[2 * p + 1] & 0xFFFF0000u);
    }
    *(bf16x8*)&lH[bufi][er0 * 64 + sl0] = lo.v;
    *(bf16x8*)&lH[bufi][er1 * 64 + sl1] = hi.v;
  };
  auto GLOADX = [&](int g, int bufi) {
#pragma unroll
    for (int i = 0; i < 4; ++i) {
      int c = w * 4 + i;
      gload16(xTb + (size_t)(8 * c + lrow) * XTB_S + g * 64 + bswz,
              &lX[bufi][c * 512]);
    }
  };

  LOADH(g0); GLOADX(g0, 0); WRITEH(0);
  __syncthreads();
  int cur = 0;
  for (int it = g0; it < g1; ++it) {
    bool hn = it + 1 < g1;
    if (hn) { LOADH(it + 1); GLOADX(it + 1, cur ^ 1); }
    const int kg = lane >> 4, fr = lane & 15;
    bf16x8 ax[4][2], bh[2][2];
#pragma unroll
    for (int mi = 0; mi < 4; ++mi) {
      int m = wy * 64 + mi * 16 + fr;
#pragma unroll
      for (int kk = 0; kk < 2; ++kk)
        ax[mi][kk] = *(const bf16x8*)&lX[cur][m * 64 + (((kk * 4 + kg) ^ (m & 7)) << 3)];
    }
#pragma unroll
    for (int ni = 0; ni < 2; ++ni) {
      int n = wx * 32 + ni * 16 + fr;
#pragma unroll
      for (int kk = 0; kk < 2; ++kk)
        bh[ni][kk] = *(const bf16x8*)&lH[cur][n * 64 + (((kk * 4 + kg) ^ (n & 7)) << 3)];
    }
#pragma unroll
    for (int kk = 0; kk < 2; ++kk)
#pragma unroll
      for (int mi = 0; mi < 4; ++mi)
#pragma unroll
        for (int ni = 0; ni < 2; ++ni)
          acc[mi][ni] = __builtin_amdgcn_mfma_f32_16x16x32_bf16(ax[mi][kk], bh[ni][kk], acc[mi][ni], 0, 0, 0);
    if (wy == 0) {
#pragma unroll
      for (int kk = 0; kk < 2; ++kk)
#pragma unroll
        for (int ni = 0; ni < 2; ++ni)
          accC[ni] = __builtin_amdgcn_mfma_f32_16x16x32_bf16(ones, bh[ni][kk], accC[ni], 0, 0, 0);
    }
    if (hn) WRITEH(cur ^ 1);
    __syncthreads();
    cur ^= 1;
  }
  const int kg = lane >> 4, fr = lane & 15;
  if (wy == 0 && kg == 0) {                   // colsum partial (rows identical)
#pragma unroll
    for (int ni = 0; ni < 2; ++ni)
      desumP[s * E_ + e0 + wx * 32 + ni * 16 + fr] = accC[ni][0];
  }
#pragma unroll
  for (int mi = 0; mi < 4; ++mi)
#pragma unroll
    for (int ni = 0; ni < 2; ++ni)
#pragma unroll
      for (int r = 0; r < 4; ++r) {
        int d = wy * 64 + mi * 16 + kg * 4 + r;
        int e = e0 + wx * 32 + ni * 16 + fr;
        partialT[((size_t)s * 128 + d) * E_ + e] = acc[mi][ni][r];
      }
}

// ---------------------------------------------------------------------------
// k_mid: x3WT[j][e] = sum_d W[j][d] * (de[e] * sum_s partialT[s][d][e])
// 256 blocks x 16 e.
// ---------------------------------------------------------------------------
__global__ __launch_bounds__(256) void k_mid(const float* __restrict__ partialT,
                                             const float* __restrict__ desumP,
                                             const unsigned short* __restrict__ Wb,
                                             unsigned short* __restrict__ x3WT) {
  __shared__ unsigned short lW[128 * 136];    // [j][d] padded
  __shared__ unsigned short lE[16 * 132];     // [e][d] padded
  __shared__ float lT[128 * 20];              // [j][e] padded
  const int t = threadIdx.x, lane = t & 63, w = t >> 6;
  const int e0 = blockIdx.x * 16;

  {                                           // stage Wb -> lW
    int j = t >> 1, half = (t & 1) * 64;
    const us8* src = (const us8*)(Wb + (size_t)j * 128 + half);
#pragma unroll
    for (int i = 0; i < 8; ++i)
      *(us8*)&lW[j * 136 + half + 8 * i] = src[i];
  }
  {                                           // phase 1: reduce + de-scale
    const int e = e0 + (t & 15);
    const int d0 = (t >> 4) * 8;
    float des = 0.f;
#pragma unroll
    for (int s = 0; s < SPLIT; ++s) des += desumP[s * E_ + e];
    float dei = des > 0.f ? 1.f / des : 0.f;
    float accp[8];
#pragma unroll
    for (int i = 0; i < 8; ++i) accp[i] = 0.f;
#pragma unroll
    for (int s = 0; s < SPLIT; ++s) {
      const float* p = partialT + ((size_t)s * 128 + d0) * E_ + e;
#pragma unroll
      for (int i = 0; i < 8; ++i) accp[i] += p[(size_t)i * E_];
    }
    union { bf16x8 v; unsigned u[4]; } un;
#pragma unroll
    for (int i = 0; i < 4; ++i)
      un.u[i] = cvtpk(accp[2 * i] * dei, accp[2 * i + 1] * dei);
    *(bf16x8*)&lE[(t & 15) * 132 + d0] = un.v;
  }
  __syncthreads();
  // phase 2: D[j][e] = W @ x3^T ; 4 waves x (32j x 16e), K=128
  const int kg = lane >> 4, fr = lane & 15;
  f32x4 acc[2];
  acc[0] = (f32x4){0.f, 0.f, 0.f, 0.f};
  acc[1] = (f32x4){0.f, 0.f, 0.f, 0.f};
#pragma unroll
  for (int kk = 0; kk < 4; ++kk) {
    bf16x8 bfrag = *(const bf16x8*)&lE[fr * 132 + (kk * 4 + kg) * 8];
#pragma unroll
    for (int mi = 0; mi < 2; ++mi) {
      int m = w * 32 + mi * 16 + fr;
      bf16x8 afrag = *(const bf16x8*)&lW[m * 136 + (kk * 4 + kg) * 8];
      acc[mi] = __builtin_amdgcn_mfma_f32_16x16x32_bf16(afrag, bfrag, acc[mi], 0, 0, 0);
    }
  }
  __syncthreads();
#pragma unroll
  for (int mi = 0; mi < 2; ++mi)
#pragma unroll
    for (int r = 0; r < 4; ++r)
      lT[(w * 32 + mi * 16 + kg * 4 + r) * 20 + fr] = acc[mi][r];
  __syncthreads();
  {
    int j = t >> 1, eh = (t & 1) * 8;
    float v[8];
#pragma unroll
    for (int i = 0; i < 8; ++i) v[i] = lT[j * 20 + eh + i];
    union { us8 v8; unsigned u[4]; } un;
#pragma unroll
    for (int i = 0; i < 4; ++i) un.u[i] = cvtpk(v[2 * i], v[2 * i + 1]);
    *(us8*)(x3WT + (size_t)j * E_ + e0 + eh) = un.v8;
  }
}

// ---------------------------------------------------------------------------
// GEMM2 (split-K=2): P[h][n][j] = sum_{e in half h} Hb[n][e]*x3WT[j][e]
// R8 structure verbatim (64n x 128j, BK=64, 2-deep, __syncthreads), but each
// block does 32 K-steps. grid 626 -> path 96 steps (was 128), HBM spread even.
// ---------------------------------------------------------------------------
__global__ __launch_bounds__(256) void k_gemm2(const unsigned short* __restrict__ Hb,
                                               const unsigned short* __restrict__ x3WT,
                                               float* __restrict__ P) {
  __shared__ unsigned short lA[2][64 * 64];   // [n][e] swizzled content
  __shared__ unsigned short lB[2][128 * 64];  // [j][e] swizzled content
  const int t = threadIdx.x, lane = t & 63, w = t >> 6;
  const int tile = blockIdx.x >> 1, half = blockIdx.x & 1;
  const int n0b = tile * 64;
  const int gbase = half * 32;                // K-step origin
  const int lrow = lane >> 3, lslot = lane & 7;
  const int bswz = (lslot ^ lrow) << 3;
  const int wy = w >> 1, wx = w & 1;          // wy: n-half(32), wx: j-half(64)

  auto GLOADA = [&](int g, int bufi) {
#pragma unroll
    for (int i = 0; i < 2; ++i) {
      int c = w * 2 + i;
      gload16(Hb + (size_t)(n0b + 8 * c + lrow) * E_ + g * 64 + bswz,
              &lA[bufi][c * 512]);
    }
  };
  auto GLOADB = [&](int g, int bufi) {
#pragma unroll
    for (int i = 0; i < 4; ++i) {
      int c = w * 4 + i;
      gload16(x3WT + (size_t)(8 * c + lrow) * E_ + g * 64 + bswz,
              &lB[bufi][c * 512]);
    }
  };

  f32x4 acc[2][4];
#pragma unroll
  for (int i = 0; i < 2; ++i)
#pragma unroll
    for (int j = 0; j < 4; ++j) acc[i][j] = (f32x4){0.f, 0.f, 0.f, 0.f};

  GLOADA(gbase, 0); GLOADB(gbase, 0);
  __syncthreads();
  int cur = 0;
  for (int it = 0; it < 32; ++it) {
    bool hn = it < 31;
    if (hn) { GLOADA(gbase + it + 1, cur ^ 1); GLOADB(gbase + it + 1, cur ^ 1); }
    const int kg = lane >> 4, fr = lane & 15;
    bf16x8 af[2][2], bfr[4][2];
#pragma unroll
    for (int mi = 0; mi < 2; ++mi) {
      int m = wy * 32 + mi * 16 + fr;
#pragma unroll
      for (int kk = 0; kk < 2; ++kk)
        af[mi][kk] = *(const bf16x8*)&lA[cur][m * 64 + (((kk * 4 + kg) ^ (m & 7)) << 3)];
    }
#pragma unroll
    for (int ni = 0; ni < 4; ++ni) {
      int d = wx * 64 + ni * 16 + fr;
#pragma unroll
      for (int kk = 0; kk < 2; ++kk)
        bfr[ni][kk] = *(const bf16x8*)&lB[cur][d * 64 + (((kk * 4 + kg) ^ (d & 7)) << 3)];
    }
#pragma unroll
    for (int kk = 0; kk < 2; ++kk)
#pragma unroll
      for (int mi = 0; mi < 2; ++mi)
#pragma unroll
        for (int ni = 0; ni < 4; ++ni)
          acc[mi][ni] = __builtin_amdgcn_mfma_f32_16x16x32_bf16(af[mi][kk], bfr[ni][kk], acc[mi][ni], 0, 0, 0);
    __syncthreads();
    cur ^= 1;
  }
  // partial store (f32, no dv/bias -- k_out applies them)
  const int kg = lane >> 4, fr = lane & 15;
  float* Ph = P + (size_t)half * N_ * D_;
#pragma unroll
  for (int mi = 0; mi < 2; ++mi)
#pragma unroll
    for (int ni = 0; ni < 4; ++ni) {
      int j2 = wx * 64 + ni * 16 + fr;
#pragma unroll
      for (int r = 0; r < 4; ++r) {
        int n = n0b + wy * 32 + mi * 16 + kg * 4 + r;
        if (n < N_) Ph[(size_t)n * D_ + j2] = acc[mi][ni][r];
      }
    }
}

// ---------------------------------------------------------------------------
// k_out: out[n][j] = dv[n]*(P0[n][j]+P1[n][j]) + b[j].  grid 1250 x 256.
// ---------------------------------------------------------------------------
__global__ __launch_bounds__(256) void k_out(const float* __restrict__ P,
                                             const float* __restrict__ dv,
                                             const float* __restrict__ bias,
                                             float* __restrict__ out) {
  int tid = blockIdx.x * 256 + threadIdx.x;   // 320000 threads, 8 elems each
  int n = tid >> 4, jb = (tid & 15) * 8;
  size_t off = (size_t)n * D_ + jb;
  f32x4 p0a = *(const f32x4*)(P + off);
  f32x4 p0b = *(const f32x4*)(P + off + 4);
  f32x4 p1a = *(const f32x4*)(P + (size_t)N_ * D_ + off);
  f32x4 p1b = *(const f32x4*)(P + (size_t)N_ * D_ + off + 4);
  f32x4 ba  = *(const f32x4*)(bias + jb);
  f32x4 bb  = *(const f32x4*)(bias + jb + 4);
  float d = dv[n];
  f32x4 oa = (p0a + p1a) * d + ba;
  f32x4 ob = (p0b + p1b) * d + bb;
  *(f32x4*)(out + off)     = oa;
  *(f32x4*)(out + off + 4) = ob;
}

// ---------------------------------------------------------------------------
extern "C" void kernel_launch(void* const* d_in, const int* in_sizes, int n_in,
                              void* d_out, int out_size, void* d_ws, size_t ws_size,
                              hipStream_t stream) {
  const float* x = (const float*)d_in[0];
  const float* H = (const float*)d_in[1];
  const float* W = (const float*)d_in[2];
  const float* b = (const float*)d_in[3];
  float* out = (float*)d_out;
  char* ws = (char*)d_ws;
  float*          desumP   = (float*)(ws);                     // 12*4096*4 = 196,608
  float*          dv       = (float*)(ws + 196608);            // 80,128
  unsigned short* Wb       = (unsigned short*)(ws + 276736);   // 32,768
  unsigned short* xTb      = (unsigned short*)(ws + 309504);   // 5,128,192
  unsigned short* x3WT     = (unsigned short*)(ws + 5437696);  // 1,048,576
  float*          partialT = (float*)(ws + 6486272);           // 25,165,824
  unsigned short* Hb       = (unsigned short*)(ws + 31652096); // 20032*4096*2 = 164,102,144
  float*          P        = (float*)(ws + 195754240);         // 2*20000*128*4 = 20,480,000

  k_pre<<<2504, 256, 0, stream>>>(H, x, W, dv, Hb, xTb, Wb);
  k_gemm1<<<768, 256, 0, stream>>>(Hb, xTb, partialT, desumP);
  k_mid<<<256, 256, 0, stream>>>(partialT, desumP, Wb, x3WT);
  k_gemm2<<<626, 256, 0, stream>>>(Hb, x3WT, P);
  k_out<<<1250, 256, 0, stream>>>(P, dv, b, out);
}